// Round 5
// baseline (21.640 us; speedup 1.0000x reference)
//
#include <hip/hip_runtime.h>

// Path signature depth 4, path (N=64, L=512, C=8) fp32.
// Output per batch: levels 1..4 concat -> 8 + 64 + 512 + 4096 = 4680 floats.
//
// k1: 512 blocks = (n, g in 0..7). Wave w: 16-step chunk signature in regs
//     (lane (a,b) owns S4[a][b][*][*]). In-block 4-way combine via LDS with
//     2 ping-pong L4 exchange buffers -> partial sig (1/8 batch) -> ws.
// k2: 64 blocks; combines the 8 partials serially -> out.
//
// LDS layouts for L123 (bank-conflict-free):
//   A-side (scalar access):  L1 flat [0,8), L2 flat [8,72), L3 at 72+(p*8+q)*9+r
//   B-side (float4 access):  L1/L2 flat,                L3 at 72+x*72+y*8+z
// L4 transposed exchange/ws layout: float4 #i of lane l at f4-index i*64+l
// (consecutive-lane-consecutive-16B: conflict-free LDS, coalesced global).

#define NB 64
#define LP 512
#define SIG 4680
#define O2 8
#define O3 72
#define O4 584
#define SB 648
#define L123_F4 146

#define A3IDX(pq, r) (72 + (pq) * 9 + (r))
#define B3IDX(x, y, z) (72 + (x) * 72 + (y) * 8 + (z))

// ---------------------------------------------------------------------------
// Chen product A <- A (x) B. a4: A's 16 owned L4 elems (a,b,c=2w..2w+1,d).
// Ap/Aq: A-layout L123. B: B-layout L123. b4: B's owned L4 elems.
// ---------------------------------------------------------------------------
__device__ __forceinline__ void prod_core(
    float (&a4)[16], const float (&b4)[16],
    const float* Ap, float* Aq, const float* B,
    int tid, int w, int l, int a, int b)
{
    const int c0 = 2 * w;
    // level 4: A4[abcd] += B4 + A3[abc]B1[d] + A2[ab]B2[cd] + A1[a]B3[bcd]
    const float A1   = Ap[a];
    const float A2   = Ap[O2 + a * 8 + b];
    const float A3_0 = Ap[A3IDX(a * 8 + b, c0)];
    const float A3_1 = Ap[A3IDX(a * 8 + b, c0 + 1)];
    float b1[8];
    *(float4*)&b1[0] = *(const float4*)(B);
    *(float4*)&b1[4] = *(const float4*)(B + 4);
    float b2r[16], b3r[16];
    #pragma unroll
    for (int i = 0; i < 4; ++i) {
        *(float4*)&b2r[4 * i] = *(const float4*)(B + O2 + c0 * 8 + 4 * i);
        *(float4*)&b3r[4 * i] = *(const float4*)(B + B3IDX(b, c0, 0) + 4 * i);
    }
    #pragma unroll
    for (int cc = 0; cc < 2; ++cc) {
        const float A3c = cc ? A3_1 : A3_0;
        #pragma unroll
        for (int d = 0; d < 8; ++d)
            a4[cc * 8 + d] += b4[cc * 8 + d] + A3c * b1[d]
                            + A2 * b2r[cc * 8 + d] + A1 * b3r[cc * 8 + d];
    }
    // level 3 (elements f0, f0+1): A3[pqr] += B3 + A2[pq]B1[r] + A1[p]B2[qr]
    const int f0 = 2 * tid;
    const int pp = f0 >> 6, qq = (f0 >> 3) & 7, rr = f0 & 7;
    const float A1p  = Ap[pp];
    const float A2pq = Ap[O2 + pp * 8 + qq];
    Aq[A3IDX(pp * 8 + qq, rr)]     = Ap[A3IDX(pp * 8 + qq, rr)]
        + B[B3IDX(pp, qq, rr)]     + A2pq * B[rr]     + A1p * B[O2 + qq * 8 + rr];
    Aq[A3IDX(pp * 8 + qq, rr + 1)] = Ap[A3IDX(pp * 8 + qq, rr + 1)]
        + B[B3IDX(pp, qq, rr + 1)] + A2pq * B[rr + 1] + A1p * B[O2 + qq * 8 + rr + 1];
    // level 2 / 1
    if (tid < 64) Aq[O2 + tid] = Ap[O2 + tid] + B[O2 + tid] + Ap[tid >> 3] * B[tid & 7];
    if (tid < 8)  Aq[tid] = Ap[tid] + B[tid];
}

// ---------------------------------------------------------------------------
// k1: 512 blocks x 256 thr. 16-step chunks + in-block 4-way combine.
// ---------------------------------------------------------------------------
__global__ __launch_bounds__(256) void k1_sig(const float* __restrict__ path,
                                              float* __restrict__ ws)
{
    __shared__ __align__(16) float zbuf[64 * 8];
    __shared__ __align__(16) float sA[2][SB];
    __shared__ __align__(16) float sL1[SB], sL2[SB], sL3[SB];
    __shared__ __align__(16) float4 sTA[1024], sTB[1024];

    const int tid = threadIdx.x;
    const int n = blockIdx.x >> 3;
    const int g = blockIdx.x & 7;

    if (tid < 128) {   // stage 64 increments (zero-padded past t=510)
        const int r = tid >> 1, h = tid & 1;
        const int t = g * 64 + r;
        const float4* p4 = (const float4*)path + (size_t)n * (LP * 2);
        float4 z4 = make_float4(0.f, 0.f, 0.f, 0.f);
        if (t < LP - 1) {
            float4 x0 = p4[t * 2 + h];
            float4 x1 = p4[t * 2 + 2 + h];
            z4 = make_float4(x1.x - x0.x, x1.y - x0.y, x1.z - x0.z, x1.w - x0.w);
        }
        ((float4*)zbuf)[tid] = z4;
    }
    __syncthreads();

    const int w = tid >> 6, l = tid & 63;
    const int a = l >> 3, b = l & 7;
    const int f0 = 2 * tid;

    // ---- 16-step chunk signature in registers ----
    float s1 = 0.f, s2 = 0.f, s3[8], s4[64];
    #pragma unroll
    for (int c = 0; c < 8; ++c) s3[c] = 0.f;
    #pragma unroll
    for (int e = 0; e < 64; ++e) s4[e] = 0.f;

    const float* zw = zbuf + w * (16 * 8);
    #pragma unroll 4
    for (int s = 0; s < 16; ++s) {
        const float* zs = zw + s * 8;
        float z[8];
        float4 zl = ((const float4*)zs)[0];
        float4 zh = ((const float4*)zs)[1];
        z[0]=zl.x; z[1]=zl.y; z[2]=zl.z; z[3]=zl.w;
        z[4]=zh.x; z[5]=zh.y; z[6]=zh.z; z[7]=zh.w;
        const float za  = zs[a];
        const float zbv = zs[b];
        const float B4 = zbv * (za * (1.f/24.f) + s1 * (1.f/6.f)) + s2 * 0.5f;
        const float G3 = zbv * (za * (1.f/6.f)  + s1 * 0.5f)      + s2;
        #pragma unroll
        for (int c = 0; c < 8; ++c) {
            const float Ac = B4 * z[c] + s3[c];
            #pragma unroll
            for (int d = 0; d < 8; ++d) s4[c*8+d] += Ac * z[d];
            s3[c] += G3 * z[c];
        }
        s2 += zbv * (za * 0.5f + s1);
        s1 += za;
    }

    // ---- publish: sig0 -> sA[0] (A-layout) + sTA; sig1 -> sL1 + sTB;
    //               sig2 -> sL2; sig3 -> sL3 (L4 of 2,3 stay in regs) ----
    if (w == 0) {
        if (b == 0) sA[0][a] = s1;
        sA[0][O2 + l] = s2;
        #pragma unroll
        for (int c = 0; c < 8; ++c) sA[0][A3IDX(l, c)] = s3[c];
        #pragma unroll
        for (int i = 0; i < 16; ++i)
            sTA[i * 64 + l] = make_float4(s4[4*i], s4[4*i+1], s4[4*i+2], s4[4*i+3]);
    } else {
        float* SL = (w == 1) ? sL1 : (w == 2) ? sL2 : sL3;
        if (b == 0) SL[a] = s1;
        SL[O2 + l] = s2;
        *(float4*)&SL[B3IDX(a, b, 0)] = make_float4(s3[0], s3[1], s3[2], s3[3]);
        *(float4*)&SL[B3IDX(a, b, 4)] = make_float4(s3[4], s3[5], s3[6], s3[7]);
        if (w == 1) {
            #pragma unroll
            for (int i = 0; i < 16; ++i)
                sTB[i * 64 + l] = make_float4(s4[4*i], s4[4*i+1], s4[4*i+2], s4[4*i+3]);
        }
    }
    __syncthreads();

    float a4[16], b4[16];
    #pragma unroll
    for (int k = 0; k < 4; ++k) {
        float4 v = sTA[(w * 4 + k) * 64 + l];
        a4[4*k]=v.x; a4[4*k+1]=v.y; a4[4*k+2]=v.z; a4[4*k+3]=v.w;
        float4 u = sTB[(w * 4 + k) * 64 + l];
        b4[4*k]=u.x; b4[4*k+1]=u.y; b4[4*k+2]=u.z; b4[4*k+3]=u.w;
    }
    prod_core(a4, b4, sA[0], sA[1], sL1, tid, w, l, a, b);
    __syncthreads();                       // sTA free, sA[1] visible
    if (w == 2) {
        #pragma unroll
        for (int i = 0; i < 16; ++i)
            sTA[i * 64 + l] = make_float4(s4[4*i], s4[4*i+1], s4[4*i+2], s4[4*i+3]);
    }
    __syncthreads();
    #pragma unroll
    for (int k = 0; k < 4; ++k) {
        float4 u = sTA[(w * 4 + k) * 64 + l];
        b4[4*k]=u.x; b4[4*k+1]=u.y; b4[4*k+2]=u.z; b4[4*k+3]=u.w;
    }
    prod_core(a4, b4, sA[1], sA[0], sL2, tid, w, l, a, b);
    __syncthreads();                       // sTB free, sA[0] visible
    if (w == 3) {
        #pragma unroll
        for (int i = 0; i < 16; ++i)
            sTB[i * 64 + l] = make_float4(s4[4*i], s4[4*i+1], s4[4*i+2], s4[4*i+3]);
    }
    __syncthreads();
    #pragma unroll
    for (int k = 0; k < 4; ++k) {
        float4 u = sTB[(w * 4 + k) * 64 + l];
        b4[4*k]=u.x; b4[4*k+1]=u.y; b4[4*k+2]=u.z; b4[4*k+3]=u.w;
    }
    prod_core(a4, b4, sA[0], sA[1], sL3, tid, w, l, a, b);
    __syncthreads();

    // ---- store partial (flat L123, T-layout L4) ----
    float* dst = ws + (size_t)blockIdx.x * SIG;
    if (tid < O3) dst[tid] = sA[1][tid];
    dst[O3 + f0]     = sA[1][A3IDX(f0 >> 3, f0 & 7)];
    dst[O3 + f0 + 1] = sA[1][A3IDX(f0 >> 3, (f0 & 7) + 1)];
    float4* dT = (float4*)(dst + O4);
    #pragma unroll
    for (int k = 0; k < 4; ++k)
        dT[(w * 4 + k) * 64 + l] = make_float4(a4[4*k], a4[4*k+1], a4[4*k+2], a4[4*k+3]);
}

// ---------------------------------------------------------------------------
// k2: 64 blocks x 256 thr; combine the 8 partials -> out (true flat layout).
// ---------------------------------------------------------------------------
__global__ __launch_bounds__(256) void k2_final(const float* __restrict__ ws,
                                                float* __restrict__ out)
{
    __shared__ __align__(16) float sA[2][SB];
    __shared__ __align__(16) float sLb[7][SB];

    const int tid = threadIdx.x;
    const int n = blockIdx.x;
    const int w = tid >> 6, l = tid & 63;
    const int a = l >> 3, b = l & 7;
    const int f0 = 2 * tid;
    const float* base = ws + (size_t)n * 8 * SIG;

    // stage sig0 L123 -> sA[0] (A-layout)
    if (tid < O3) sA[0][tid] = base[tid];
    sA[0][A3IDX(f0 >> 3, f0 & 7)]       = base[O3 + f0];
    sA[0][A3IDX(f0 >> 3, (f0 & 7) + 1)] = base[O3 + f0 + 1];
    // stage sigs 1..7 L123 -> sLb (B-layout; f4-preserving remap)
    #pragma unroll
    for (int m = 1; m <= 7; ++m) {
        if (tid < L123_F4) {
            float4 v = ((const float4*)(base + (size_t)m * SIG))[tid];
            int d4;
            if (tid < 18) d4 = tid;
            else { const int j = tid - 18; d4 = 18 + (j >> 4) * 18 + (j & 15); }
            ((float4*)sLb[m - 1])[d4] = v;
        }
    }
    // own L4: a4 <- sig0, b4A <- sig1 (coalesced T-layout reads)
    float a4[16], b4A[16], b4B[16];
    #pragma unroll
    for (int k = 0; k < 4; ++k) {
        const int ti = (w * 4 + k) * 64 + l;
        float4 v = ((const float4*)(base + O4))[ti];
        a4[4*k]=v.x; a4[4*k+1]=v.y; a4[4*k+2]=v.z; a4[4*k+3]=v.w;
        float4 u = ((const float4*)(base + SIG + O4))[ti];
        b4A[4*k]=u.x; b4A[4*k+1]=u.y; b4A[4*k+2]=u.z; b4A[4*k+3]=u.w;
    }
    __syncthreads();

    #define LOADB4(dstv, mm)                                                   \
        { _Pragma("unroll")                                                    \
          for (int k = 0; k < 4; ++k) {                                        \
              float4 u = ((const float4*)(base + (size_t)(mm) * SIG + O4))     \
                             [(w * 4 + k) * 64 + l];                           \
              dstv[4*k]=u.x; dstv[4*k+1]=u.y; dstv[4*k+2]=u.z; dstv[4*k+3]=u.w;\
          } }

    LOADB4(b4B, 2); prod_core(a4, b4A, sA[0], sA[1], sLb[0], tid, w, l, a, b); __syncthreads();
    LOADB4(b4A, 3); prod_core(a4, b4B, sA[1], sA[0], sLb[1], tid, w, l, a, b); __syncthreads();
    LOADB4(b4B, 4); prod_core(a4, b4A, sA[0], sA[1], sLb[2], tid, w, l, a, b); __syncthreads();
    LOADB4(b4A, 5); prod_core(a4, b4B, sA[1], sA[0], sLb[3], tid, w, l, a, b); __syncthreads();
    LOADB4(b4B, 6); prod_core(a4, b4A, sA[0], sA[1], sLb[4], tid, w, l, a, b); __syncthreads();
    LOADB4(b4A, 7); prod_core(a4, b4B, sA[1], sA[0], sLb[5], tid, w, l, a, b); __syncthreads();
                    prod_core(a4, b4A, sA[0], sA[1], sLb[6], tid, w, l, a, b); __syncthreads();

    // store final signature (true flat layout)
    float* dst = out + (size_t)n * SIG;
    if (tid < O3) dst[tid] = sA[1][tid];
    dst[O3 + f0]     = sA[1][A3IDX(f0 >> 3, f0 & 7)];
    dst[O3 + f0 + 1] = sA[1][A3IDX(f0 >> 3, (f0 & 7) + 1)];
    float4* d4p = (float4*)(dst + O4);
    #pragma unroll
    for (int k = 0; k < 4; ++k)
        d4p[l * 16 + w * 4 + k] = make_float4(a4[4*k], a4[4*k+1], a4[4*k+2], a4[4*k+3]);
}

extern "C" void kernel_launch(void* const* d_in, const int* in_sizes, int n_in,
                              void* d_out, int out_size, void* d_ws, size_t ws_size,
                              hipStream_t stream) {
    const float* path = (const float*)d_in[0];
    float* out = (float*)d_out;
    float* ws  = (float*)d_ws;   // 512 * 4680 * 4 B = 9.58 MB used

    k1_sig<<<NB * 8, 256, 0, stream>>>(path, ws);
    k2_final<<<NB, 256, 0, stream>>>(ws, out);
}